// Round 11
// baseline (37.119 us; speedup 1.0000x reference)
//
#include <hip/hip_runtime.h>
#include <math.h>

#define CIN  64
#define HH   32
#define WW   32
#define OCH  64
#define IKK  576
#define DH   32
#define OIKK 36864
#define PSTR 588   // patch row stride (floats): 12*pp mod 32 -> 2-way banks (free)

__device__ __forceinline__ float silu_f(float v) {
    return v / (1.0f + __expf(-v));
}

// ONE dispatch, single-writer, no atomics, no memset, no inter-block sync.
// block = (b2, q64, oh2): the 16 pixels p = pp*64+q (pp in [0,16)), o-half oh.
//   patch[16][576] feeds BOTH GEMMs:
//     t[j][pp]    = patch . w2[j][q*576+:]      (w2 slab 73.7 KB, L2)
//     conv[o][pp] = patch . kern[o][:]          (kern slab 73.7 KB, L2)
//   h recomputed inline per (o,pp); out stored exactly once per element.
__global__ __launch_bounds__(256) void k_one(
    const float* __restrict__ x, const float* __restrict__ c,
    const float* __restrict__ kern, const float* __restrict__ bias,
    const float* __restrict__ w1, const float* __restrict__ b1,
    const float* __restrict__ w2, const float* __restrict__ b2,
    float* __restrict__ out)
{
    __shared__ __align__(16) float patch[16][PSTR];
    __shared__ float tred[2][8][4][16];   // [kq][jg][jj][pp]
    __shared__ float cred[2][8][4][16];   // [kq][og][jj][pp]
    __shared__ float spart[16][17];
    __shared__ float t_sm[DH][17];
    __shared__ float conv_sm[32][17];
    __shared__ float s_sm[16];

    int tid = threadIdx.x;
    int bid = blockIdx.x;
    int oh  = bid & 1;
    int q   = (bid >> 1) & 63;
    int b   = bid >> 7;
    int par = q >> 5, xq = q & 31;

    // ---- stage 16 patches: pixel pp -> (y,x) = (2*pp+par, xq) ----
    for (int idx = tid; idx < 16 * IKK; idx += 256) {
        int pp  = idx / IKK;
        int ikk = idx - pp * IKK;
        int ci  = ikk / 9;
        int r   = ikk - ci * 9;
        int kh  = r / 3;
        int kw  = r - kh * 3;
        int yy  = 2 * pp + par + kh - 1;
        int xx  = xq + kw - 1;
        float v = 0.0f;
        if (yy >= 0 && yy < HH && xx >= 0 && xx < WW)
            v = x[((b * CIN + ci) * HH + yy) * WW + xx];
        patch[pp][ikk] = v;
    }
    __syncthreads();

    int kq = tid >> 7;          // 0..1  (K-half: 288 floats = 72 float4)
    int g4 = (tid >> 4) & 7;    // 0..7  (j-group in T, o-group in C)
    int pp = tid & 15;

    // ---- Phase T: t partials (4 j per thread) ----
    {
        const float4* pr  = (const float4*)(&patch[pp][0]) + kq * 72;
        const float*  wb  = w2 + (size_t)q * IKK + (size_t)kq * 288;
        const float4* wp0 = (const float4*)(wb + (size_t)(g4 * 4 + 0) * OIKK);
        const float4* wp1 = (const float4*)(wb + (size_t)(g4 * 4 + 1) * OIKK);
        const float4* wp2 = (const float4*)(wb + (size_t)(g4 * 4 + 2) * OIKK);
        const float4* wp3 = (const float4*)(wb + (size_t)(g4 * 4 + 3) * OIKK);
        float4 a0 = {0,0,0,0}, a1 = {0,0,0,0}, a2 = {0,0,0,0}, a3 = {0,0,0,0};
        #pragma unroll 4
        for (int it = 0; it < 72; ++it) {
            float4 pv = pr[it];
            float4 u0 = wp0[it], u1 = wp1[it], u2 = wp2[it], u3 = wp3[it];
            a0.x = fmaf(u0.x, pv.x, a0.x); a0.y = fmaf(u0.y, pv.y, a0.y);
            a0.z = fmaf(u0.z, pv.z, a0.z); a0.w = fmaf(u0.w, pv.w, a0.w);
            a1.x = fmaf(u1.x, pv.x, a1.x); a1.y = fmaf(u1.y, pv.y, a1.y);
            a1.z = fmaf(u1.z, pv.z, a1.z); a1.w = fmaf(u1.w, pv.w, a1.w);
            a2.x = fmaf(u2.x, pv.x, a2.x); a2.y = fmaf(u2.y, pv.y, a2.y);
            a2.z = fmaf(u2.z, pv.z, a2.z); a2.w = fmaf(u2.w, pv.w, a2.w);
            a3.x = fmaf(u3.x, pv.x, a3.x); a3.y = fmaf(u3.y, pv.y, a3.y);
            a3.z = fmaf(u3.z, pv.z, a3.z); a3.w = fmaf(u3.w, pv.w, a3.w);
        }
        tred[kq][g4][0][pp] = (a0.x + a0.y) + (a0.z + a0.w);
        tred[kq][g4][1][pp] = (a1.x + a1.y) + (a1.z + a1.w);
        tred[kq][g4][2][pp] = (a2.x + a2.y) + (a2.z + a2.w);
        tred[kq][g4][3][pp] = (a3.x + a3.y) + (a3.z + a3.w);
    }

    // ---- Phase C: conv partials (4 o per thread, same shape vs kern) ----
    {
        int ob = oh * 32 + g4 * 4;
        const float4* pr  = (const float4*)(&patch[pp][0]) + kq * 72;
        const float4* kp0 = (const float4*)(kern + (size_t)(ob + 0) * IKK + kq * 288);
        const float4* kp1 = (const float4*)(kern + (size_t)(ob + 1) * IKK + kq * 288);
        const float4* kp2 = (const float4*)(kern + (size_t)(ob + 2) * IKK + kq * 288);
        const float4* kp3 = (const float4*)(kern + (size_t)(ob + 3) * IKK + kq * 288);
        float4 a0 = {0,0,0,0}, a1 = {0,0,0,0}, a2 = {0,0,0,0}, a3 = {0,0,0,0};
        #pragma unroll 4
        for (int it = 0; it < 72; ++it) {
            float4 pv = pr[it];
            float4 u0 = kp0[it], u1 = kp1[it], u2 = kp2[it], u3 = kp3[it];
            a0.x = fmaf(u0.x, pv.x, a0.x); a0.y = fmaf(u0.y, pv.y, a0.y);
            a0.z = fmaf(u0.z, pv.z, a0.z); a0.w = fmaf(u0.w, pv.w, a0.w);
            a1.x = fmaf(u1.x, pv.x, a1.x); a1.y = fmaf(u1.y, pv.y, a1.y);
            a1.z = fmaf(u1.z, pv.z, a1.z); a1.w = fmaf(u1.w, pv.w, a1.w);
            a2.x = fmaf(u2.x, pv.x, a2.x); a2.y = fmaf(u2.y, pv.y, a2.y);
            a2.z = fmaf(u2.z, pv.z, a2.z); a2.w = fmaf(u2.w, pv.w, a2.w);
            a3.x = fmaf(u3.x, pv.x, a3.x); a3.y = fmaf(u3.y, pv.y, a3.y);
            a3.z = fmaf(u3.z, pv.z, a3.z); a3.w = fmaf(u3.w, pv.w, a3.w);
        }
        cred[kq][g4][0][pp] = (a0.x + a0.y) + (a0.z + a0.w);
        cred[kq][g4][1][pp] = (a1.x + a1.y) + (a1.z + a1.w);
        cred[kq][g4][2][pp] = (a2.x + a2.y) + (a2.z + a2.w);
        cred[kq][g4][3][pp] = (a3.x + a3.y) + (a3.z + a3.w);
    }

    // ---- Phase S: s partials (16 pp x 16 K-chunks of 36) ----
    {
        int spp = tid >> 4, kc = tid & 15;
        const float* b2q = b2 + q * IKK + kc * 36;
        const float* pq  = &patch[spp][kc * 36];
        float acc = 0.f;
        #pragma unroll
        for (int i = 0; i < 36; ++i) acc = fmaf(pq[i], b2q[i], acc);
        spart[spp][kc] = acc;
    }
    __syncthreads();

    // ---- reductions ----
    for (int i = tid; i < 512; i += 256) {
        int j = i >> 4, p2 = i & 15;
        t_sm[j][p2] = tred[0][j >> 2][j & 3][p2] + tred[1][j >> 2][j & 3][p2];
    }
    for (int i = tid; i < 512; i += 256) {
        int o = i >> 4, p2 = i & 15;
        conv_sm[o][p2] = cred[0][o >> 2][o & 3][p2] + cred[1][o >> 2][o & 3][p2];
    }
    if (tid < 16) {
        float a = 0.f;
        #pragma unroll
        for (int kc = 0; kc < 16; ++kc) a += spart[tid][kc];
        s_sm[tid] = a;
    }
    __syncthreads();

    // ---- Phase H: inline MLP + dyn + store (exactly one store per out elem) ----
    {
        int o  = tid & 31;     // local o
        int pg = tid >> 5;     // 0..7
        int og = oh * 32 + o;
        float cb[8];
        #pragma unroll
        for (int i = 0; i < 8; ++i) cb[i] = c[(b << 3) + i];
        float bo = bias[og];
        #pragma unroll
        for (int h2 = 0; h2 < 2; ++h2) {
            int p2 = pg + (h2 << 3);
            int pl = (og << 4) + p2;
            float f0 = (float)(pl >> 5) * (1.0f / 32.0f);
            float f1 = (float)(pl & 31) * (1.0f / 32.0f);
            float dyn = s_sm[p2];
            #pragma unroll 4
            for (int j = 0; j < DH; ++j) {
                float v = b1[j];
                v = fmaf(f0, w1[j], v);
                v = fmaf(f1, w1[DH + j], v);
                #pragma unroll
                for (int i = 0; i < 8; ++i)
                    v = fmaf(cb[i], w1[(2 + i) * DH + j], v);
                dyn = fmaf(silu_f(v), t_sm[j][p2], dyn);
            }
            out[((b * OCH + og) << 10) + (p2 << 6) + q] = conv_sm[o][p2] + bo + dyn;
        }
    }
}

extern "C" void kernel_launch(void* const* d_in, const int* in_sizes, int n_in,
                              void* d_out, int out_size, void* d_ws, size_t ws_size,
                              hipStream_t stream) {
    const float* x    = (const float*)d_in[0];
    const float* c    = (const float*)d_in[1];
    const float* kern = (const float*)d_in[2];
    const float* bias = (const float*)d_in[3];
    const float* w1   = (const float*)d_in[4];
    const float* b1   = (const float*)d_in[5];
    const float* w2   = (const float*)d_in[6];
    const float* b2   = (const float*)d_in[7];
    float* out = (float*)d_out;

    k_one<<<256, 256, 0, stream>>>(x, c, kern, bias, w1, b1, w2, b2, out);
}

// Round 13
// 32.928 us; speedup vs baseline: 1.1273x; 1.1273x over previous
//
#include <hip/hip_runtime.h>
#include <math.h>

#define CIN  64
#define HH   32
#define WW   32
#define OCH  64
#define IKK  576
#define DH   32
#define OIKK 36864
#define PSTR 588   // patch row stride (floats)

__device__ __forceinline__ float silu_f(float v) {
    return v / (1.0f + __expf(-v));
}

// ONE dispatch, single-writer, no atomics/memset/sync.
// block = (b2, q64, oh2) = 256 blocks x 512 threads (8 waves/CU, 2/SIMD).
// Fused T+C main loop: per iter 1 patch b128 + 4 w2 + 4 kern float4 streams.
__global__ __launch_bounds__(512) void k_one(
    const float* __restrict__ x, const float* __restrict__ c,
    const float* __restrict__ kern, const float* __restrict__ bias,
    const float* __restrict__ w1, const float* __restrict__ b1,
    const float* __restrict__ w2, const float* __restrict__ b2,
    float* __restrict__ out)
{
    __shared__ __align__(16) float patch[16][PSTR];
    __shared__ float tred[4][8][4][16];   // [kq][jg][jj][pp]
    __shared__ float cred[4][8][4][16];   // [kq][og][jj][pp]
    __shared__ float spart[16][33];
    __shared__ float t_sm[DH][17];
    __shared__ float conv_sm[32][17];
    __shared__ float s_sm[16];

    int tid = threadIdx.x;
    int bid = blockIdx.x;
    int oh  = bid & 1;
    int q   = (bid >> 1) & 63;
    int b   = bid >> 7;
    int par = q >> 5, xq = q & 31;

    // ---- stage 16 patches: pixel pp -> (y,x) = (2*pp+par, xq) ----
    for (int idx = tid; idx < 16 * IKK; idx += 512) {
        int pp  = idx / IKK;
        int ikk = idx - pp * IKK;
        int ci  = ikk / 9;
        int r   = ikk - ci * 9;
        int kh  = r / 3;
        int kw  = r - kh * 3;
        int yy  = 2 * pp + par + kh - 1;
        int xx  = xq + kw - 1;
        float v = 0.0f;
        if (yy >= 0 && yy < HH && xx >= 0 && xx < WW)
            v = x[((b * CIN + ci) * HH + yy) * WW + xx];
        patch[pp][ikk] = v;
    }
    __syncthreads();

    int kq = tid >> 7;          // 0..3  (K-quarter: 144 floats = 36 float4)
    int g4 = (tid >> 4) & 7;    // 0..7  (j-group for T, o-group for C)
    int pp = tid & 15;

    // ---- Fused T+C: 36 iters x (1 LDS b128 + 8 global float4 + 32 FMA) ----
    {
        const float4* pr  = (const float4*)(&patch[pp][0]) + kq * 36;
        const float*  wb  = w2 + (size_t)q * IKK + (size_t)kq * 144;
        const float4* wp0 = (const float4*)(wb + (size_t)(g4 * 4 + 0) * OIKK);
        const float4* wp1 = (const float4*)(wb + (size_t)(g4 * 4 + 1) * OIKK);
        const float4* wp2 = (const float4*)(wb + (size_t)(g4 * 4 + 2) * OIKK);
        const float4* wp3 = (const float4*)(wb + (size_t)(g4 * 4 + 3) * OIKK);
        int ob = oh * 32 + g4 * 4;
        const float* kb = kern + (size_t)kq * 144;
        const float4* kp0 = (const float4*)(kb + (size_t)(ob + 0) * IKK);
        const float4* kp1 = (const float4*)(kb + (size_t)(ob + 1) * IKK);
        const float4* kp2 = (const float4*)(kb + (size_t)(ob + 2) * IKK);
        const float4* kp3 = (const float4*)(kb + (size_t)(ob + 3) * IKK);
        float4 t0 = {0,0,0,0}, t1 = {0,0,0,0}, t2 = {0,0,0,0}, t3 = {0,0,0,0};
        float4 c0 = {0,0,0,0}, c1 = {0,0,0,0}, c2 = {0,0,0,0}, c3 = {0,0,0,0};
        #pragma unroll 4
        for (int it = 0; it < 36; ++it) {
            float4 pv = pr[it];
            float4 u0 = wp0[it], u1 = wp1[it], u2 = wp2[it], u3 = wp3[it];
            float4 v0 = kp0[it], v1 = kp1[it], v2 = kp2[it], v3 = kp3[it];
            t0.x = fmaf(u0.x, pv.x, t0.x); t0.y = fmaf(u0.y, pv.y, t0.y);
            t0.z = fmaf(u0.z, pv.z, t0.z); t0.w = fmaf(u0.w, pv.w, t0.w);
            t1.x = fmaf(u1.x, pv.x, t1.x); t1.y = fmaf(u1.y, pv.y, t1.y);
            t1.z = fmaf(u1.z, pv.z, t1.z); t1.w = fmaf(u1.w, pv.w, t1.w);
            t2.x = fmaf(u2.x, pv.x, t2.x); t2.y = fmaf(u2.y, pv.y, t2.y);
            t2.z = fmaf(u2.z, pv.z, t2.z); t2.w = fmaf(u2.w, pv.w, t2.w);
            t3.x = fmaf(u3.x, pv.x, t3.x); t3.y = fmaf(u3.y, pv.y, t3.y);
            t3.z = fmaf(u3.z, pv.z, t3.z); t3.w = fmaf(u3.w, pv.w, t3.w);
            c0.x = fmaf(v0.x, pv.x, c0.x); c0.y = fmaf(v0.y, pv.y, c0.y);
            c0.z = fmaf(v0.z, pv.z, c0.z); c0.w = fmaf(v0.w, pv.w, c0.w);
            c1.x = fmaf(v1.x, pv.x, c1.x); c1.y = fmaf(v1.y, pv.y, c1.y);
            c1.z = fmaf(v1.z, pv.z, c1.z); c1.w = fmaf(v1.w, pv.w, c1.w);
            c2.x = fmaf(v2.x, pv.x, c2.x); c2.y = fmaf(v2.y, pv.y, c2.y);
            c2.z = fmaf(v2.z, pv.z, c2.z); c2.w = fmaf(v2.w, pv.w, c2.w);
            c3.x = fmaf(v3.x, pv.x, c3.x); c3.y = fmaf(v3.y, pv.y, c3.y);
            c3.z = fmaf(v3.z, pv.z, c3.z); c3.w = fmaf(v3.w, pv.w, c3.w);
        }
        tred[kq][g4][0][pp] = (t0.x + t0.y) + (t0.z + t0.w);
        tred[kq][g4][1][pp] = (t1.x + t1.y) + (t1.z + t1.w);
        tred[kq][g4][2][pp] = (t2.x + t2.y) + (t2.z + t2.w);
        tred[kq][g4][3][pp] = (t3.x + t3.y) + (t3.z + t3.w);
        cred[kq][g4][0][pp] = (c0.x + c0.y) + (c0.z + c0.w);
        cred[kq][g4][1][pp] = (c1.x + c1.y) + (c1.z + c1.w);
        cred[kq][g4][2][pp] = (c2.x + c2.y) + (c2.z + c2.w);
        cred[kq][g4][3][pp] = (c3.x + c3.y) + (c3.z + c3.w);
    }

    // ---- Phase S: s partials (16 pp x 32 K-chunks of 18) ----
    {
        int spp = tid >> 5, kc = tid & 31;
        const float* b2q = b2 + q * IKK + kc * 18;
        const float* pq  = &patch[spp][kc * 18];
        float acc = 0.f;
        #pragma unroll
        for (int i = 0; i < 18; ++i) acc = fmaf(pq[i], b2q[i], acc);
        spart[spp][kc] = acc;
    }
    __syncthreads();

    // ---- reductions (each thread exactly one element) ----
    {
        int j = tid >> 4, p2 = tid & 15;   // j 0..31
        int jg = j >> 2, jj = j & 3;
        t_sm[j][p2] = (tred[0][jg][jj][p2] + tred[1][jg][jj][p2])
                    + (tred[2][jg][jj][p2] + tred[3][jg][jj][p2]);
        conv_sm[j][p2] = (cred[0][jg][jj][p2] + cred[1][jg][jj][p2])
                       + (cred[2][jg][jj][p2] + cred[3][jg][jj][p2]);
    }
    if (tid < 16) {
        float a = 0.f;
        #pragma unroll
        for (int kc = 0; kc < 32; ++kc) a += spart[tid][kc];
        s_sm[tid] = a;
    }
    __syncthreads();

    // ---- Phase H: inline MLP + dyn + store (1 output/thread) ----
    {
        int o  = tid & 31;     // local o
        int p2 = tid >> 5;     // 0..15
        int og = oh * 32 + o;
        float cb[8];
        #pragma unroll
        for (int i = 0; i < 8; ++i) cb[i] = c[(b << 3) + i];
        int pl = (og << 4) + p2;
        float f0 = (float)(pl >> 5) * (1.0f / 32.0f);
        float f1 = (float)(pl & 31) * (1.0f / 32.0f);
        float dyn = s_sm[p2];
        #pragma unroll 4
        for (int j = 0; j < DH; ++j) {
            float v = b1[j];
            v = fmaf(f0, w1[j], v);
            v = fmaf(f1, w1[DH + j], v);
            #pragma unroll
            for (int i = 0; i < 8; ++i)
                v = fmaf(cb[i], w1[(2 + i) * DH + j], v);
            dyn = fmaf(silu_f(v), t_sm[j][p2], dyn);
        }
        out[((b * OCH + og) << 10) + (p2 << 6) + q] = conv_sm[o][p2] + bias[og] + dyn;
    }
}

extern "C" void kernel_launch(void* const* d_in, const int* in_sizes, int n_in,
                              void* d_out, int out_size, void* d_ws, size_t ws_size,
                              hipStream_t stream) {
    const float* x    = (const float*)d_in[0];
    const float* c    = (const float*)d_in[1];
    const float* kern = (const float*)d_in[2];
    const float* bias = (const float*)d_in[3];
    const float* w1   = (const float*)d_in[4];
    const float* b1   = (const float*)d_in[5];
    const float* w2   = (const float*)d_in[6];
    const float* b2   = (const float*)d_in[7];
    float* out = (float*)d_out;

    k_one<<<256, 512, 0, stream>>>(x, c, kern, bias, w1, b1, w2, b2, out);
}

// Round 14
// 27.932 us; speedup vs baseline: 1.3289x; 1.1788x over previous
//
#include <hip/hip_runtime.h>
#include <math.h>

#define CIN  64
#define HH   32
#define WW   32
#define OCH  64
#define IKK  576
#define DH   32
#define OIKK 36864
#define PSTR 588   // patch row stride (floats), 16B-mult
#define WSTR 76    // wbuf row stride (floats), 16B-mult (72 data + 4 pad)

__device__ __forceinline__ float silu_f(float v) {
    return v / (1.0f + __expf(-v));
}

// ONE dispatch, single-writer. block = (b2,q64,oh2) = 256 x 512 threads.
// Weights (32 w2 rows + 32 kern rows = [64][576]) staged to LDS in 8 K-chunks
// of 72 floats via COALESCED loads; inner loop reads via LDS broadcast.
// Thread (rp,px) owns rows {2rp,2rp+1} x pixel px, accumulates full K.
__global__ __launch_bounds__(512) void k_one(
    const float* __restrict__ x, const float* __restrict__ c,
    const float* __restrict__ kern, const float* __restrict__ bias,
    const float* __restrict__ w1, const float* __restrict__ b1,
    const float* __restrict__ w2, const float* __restrict__ b2,
    float* __restrict__ out)
{
    __shared__ __align__(16) float patch[16][PSTR];   // 37632 B
    __shared__ __align__(16) float wbuf[64][WSTR];    // 19456 B
    __shared__ float t_sm[32][17];                    //  2176 B
    __shared__ float conv_sm[32][17];                 //  2176 B
    __shared__ float spart[16][33];                   //  2112 B
    __shared__ float s_sm[16];                        //    64 B  (~63.6 KB)

    int tid = threadIdx.x;
    int bid = blockIdx.x;
    int oh  = bid & 1;
    int q   = (bid >> 1) & 63;
    int b   = bid >> 7;
    int par = q >> 5, xq = q & 31;

    // ---- stage 16 patches: pixel pp -> (y,x) = (2*pp+par, xq) ----
    for (int idx = tid; idx < 16 * IKK; idx += 512) {
        int pp  = idx / IKK;
        int ikk = idx - pp * IKK;
        int ci  = ikk / 9;
        int r   = ikk - ci * 9;
        int kh  = r / 3;
        int kw  = r - kh * 3;
        int yy  = 2 * pp + par + kh - 1;
        int xx  = xq + kw - 1;
        float v = 0.0f;
        if (yy >= 0 && yy < HH && xx >= 0 && xx < WW)
            v = x[((b * CIN + ci) * HH + yy) * WW + xx];
        patch[pp][ikk] = v;
    }

    // ---- stage wbuf chunk 0 (coalesced: 1152 float4, 64 rows x 18 f4) ----
    {
        const int kc = 0;
        for (int idx = tid; idx < 1152; idx += 512) {
            int row = idx / 18;
            int c4  = idx - row * 18;
            const float* src = (row < 32)
                ? (w2   + (size_t)row * OIKK + q * IKK + kc * 72 + c4 * 4)
                : (kern + (size_t)((oh << 5) + row - 32) * IKK + kc * 72 + c4 * 4);
            *((float4*)&wbuf[row][c4 * 4]) = *(const float4*)src;
        }
    }
    __syncthreads();

    int rp = tid >> 4;   // 0..31 -> rows 2rp, 2rp+1
    int px = tid & 15;
    int r0 = rp << 1, r1 = r0 + 1;
    float4 a0 = {0,0,0,0}, a1 = {0,0,0,0};

    for (int kc = 0; kc < 8; ++kc) {
        // compute chunk kc
        const float4* pr = (const float4*)(&patch[px][0]) + kc * 18;
        const float4* w0 = (const float4*)(&wbuf[r0][0]);
        const float4* w1r = (const float4*)(&wbuf[r1][0]);
        #pragma unroll
        for (int it = 0; it < 18; ++it) {
            float4 pv = pr[it];
            float4 u0 = w0[it];
            float4 u1 = w1r[it];
            a0.x = fmaf(u0.x, pv.x, a0.x); a0.y = fmaf(u0.y, pv.y, a0.y);
            a0.z = fmaf(u0.z, pv.z, a0.z); a0.w = fmaf(u0.w, pv.w, a0.w);
            a1.x = fmaf(u1.x, pv.x, a1.x); a1.y = fmaf(u1.y, pv.y, a1.y);
            a1.z = fmaf(u1.z, pv.z, a1.z); a1.w = fmaf(u1.w, pv.w, a1.w);
        }
        if (kc < 7) {
            __syncthreads();   // everyone done reading wbuf
            int kn = kc + 1;
            for (int idx = tid; idx < 1152; idx += 512) {
                int row = idx / 18;
                int c4  = idx - row * 18;
                const float* src = (row < 32)
                    ? (w2   + (size_t)row * OIKK + q * IKK + kn * 72 + c4 * 4)
                    : (kern + (size_t)((oh << 5) + row - 32) * IKK + kn * 72 + c4 * 4);
                *((float4*)&wbuf[row][c4 * 4]) = *(const float4*)src;
            }
            __syncthreads();   // wbuf ready
        }
    }

    // results: rows 0..31 -> t[j][px]; rows 32..63 -> conv[o][px]
    {
        float v0 = (a0.x + a0.y) + (a0.z + a0.w);
        float v1 = (a1.x + a1.y) + (a1.z + a1.w);
        if (r0 < 32) { t_sm[r0][px] = v0; t_sm[r1][px] = v1; }
        else         { conv_sm[r0 - 32][px] = v0; conv_sm[r1 - 32][px] = v1; }
    }

    // ---- s partials: (16 px x 32 K-chunks of 18) ----
    {
        int spp = tid >> 5, kc = tid & 31;
        const float* b2q = b2 + q * IKK + kc * 18;
        const float* pq  = &patch[spp][kc * 18];
        float acc = 0.f;
        #pragma unroll
        for (int i = 0; i < 18; ++i) acc = fmaf(pq[i], b2q[i], acc);
        spart[spp][kc] = acc;
    }
    __syncthreads();

    if (tid < 16) {
        float a = 0.f;
        #pragma unroll
        for (int kc = 0; kc < 32; ++kc) a += spart[tid][kc];
        s_sm[tid] = a;
    }
    __syncthreads();

    // ---- H epilogue: inline MLP + dyn + store (1 output/thread) ----
    {
        int o  = tid & 31;     // local o
        int p2 = tid >> 5;     // 0..15
        int og = (oh << 5) + o;
        float cb[8];
        #pragma unroll
        for (int i = 0; i < 8; ++i) cb[i] = c[(b << 3) + i];
        int pl = (og << 4) + p2;
        float f0 = (float)(pl >> 5) * (1.0f / 32.0f);
        float f1 = (float)(pl & 31) * (1.0f / 32.0f);
        float dyn = s_sm[p2];
        #pragma unroll 4
        for (int j = 0; j < DH; ++j) {
            float v = b1[j];
            v = fmaf(f0, w1[j], v);
            v = fmaf(f1, w1[DH + j], v);
            #pragma unroll
            for (int i = 0; i < 8; ++i)
                v = fmaf(cb[i], w1[(2 + i) * DH + j], v);
            dyn = fmaf(silu_f(v), t_sm[j][p2], dyn);
        }
        out[((b * OCH + og) << 10) + (p2 << 6) + q] = conv_sm[o][p2] + bias[og] + dyn;
    }
}

extern "C" void kernel_launch(void* const* d_in, const int* in_sizes, int n_in,
                              void* d_out, int out_size, void* d_ws, size_t ws_size,
                              hipStream_t stream) {
    const float* x    = (const float*)d_in[0];
    const float* c    = (const float*)d_in[1];
    const float* kern = (const float*)d_in[2];
    const float* bias = (const float*)d_in[3];
    const float* w1   = (const float*)d_in[4];
    const float* b1   = (const float*)d_in[5];
    const float* w2   = (const float*)d_in[6];
    const float* b2   = (const float*)d_in[7];
    float* out = (float*)d_out;

    k_one<<<256, 512, 0, stream>>>(x, c, kern, bias, w1, b1, w2, b2, out);
}

// Round 15
// 22.355 us; speedup vs baseline: 1.6604x; 1.2495x over previous
//
#include <hip/hip_runtime.h>
#include <math.h>

#define CIN  64
#define HH   32
#define WW   32
#define OCH  64
#define IKK  576
#define DH   32
#define OIKK 36864
#define PF4  147   // patch row stride in float4 units (588 floats)

__device__ __forceinline__ float silu_f(float v) {
    return v / (1.0f + __expf(-v));
}

// ONE dispatch, single-writer. block = (b2,q64,oh2) = 256 x 512 threads.
// Main GEMM: thread (kq8 wave-uniform, rg16, pg4) owns 4 rows x 4 px,
// K-slice 72 floats. Weights staged per-step [64][16 f4] with XOR swizzle
// (row>>2)&7 and register prefetch. K-partials aliased onto dead patch LDS.
__global__ __launch_bounds__(512) void k_one(
    const float* __restrict__ x, const float* __restrict__ c,
    const float* __restrict__ kern, const float* __restrict__ bias,
    const float* __restrict__ w1, const float* __restrict__ b1,
    const float* __restrict__ w2, const float* __restrict__ b2,
    float* __restrict__ out)
{
    __shared__ __align__(16) float patch[16 * 4 * PF4];   // 37632 B (tred aliases later)
    __shared__ __align__(16) float wslab[64 * 16 * 4];    // 16384 B
    __shared__ float t_sm[32][17];
    __shared__ float conv_sm[32][17];
    __shared__ float spart[16][33];
    __shared__ float s_sm[16];

    int tid = threadIdx.x;
    int bid = blockIdx.x;
    int oh  = bid & 1;
    int q   = (bid >> 1) & 63;
    int b   = bid >> 7;
    int par = q >> 5, xq = q & 31;

    float4* patch4 = (float4*)patch;
    float4* wslab4 = (float4*)wslab;

    // ---- stage 16 patches: pixel pp -> (y,x) = (2*pp+par, xq) ----
    for (int idx = tid; idx < 16 * IKK; idx += 512) {
        int pp  = idx / IKK;
        int ikk = idx - pp * IKK;
        int ci  = ikk / 9;
        int r   = ikk - ci * 9;
        int kh  = r / 3;
        int kw  = r - kh * 3;
        int yy  = 2 * pp + par + kh - 1;
        int xx  = xq + kw - 1;
        float v = 0.0f;
        if (yy >= 0 && yy < HH && xx >= 0 && xx < WW)
            v = x[((b * CIN + ci) * HH + yy) * WW + xx];
        patch[pp * 4 * PF4 + ikk] = v;
    }
    __syncthreads();

    // ---- s partials FIRST (patch must be consumed before tred aliases it) ----
    {
        int spp = tid >> 5, kc = tid & 31;
        const float* b2q = b2 + q * IKK + kc * 18;
        const float* pq  = &patch[spp * 4 * PF4 + kc * 18];
        float acc = 0.f;
        #pragma unroll
        for (int i = 0; i < 18; ++i) acc = fmaf(pq[i], b2q[i], acc);
        spart[spp][kc] = acc;
    }

    // ---- main GEMM ----
    int kq = tid >> 6;          // 0..7, wave-uniform
    int rg = (tid >> 2) & 15;   // row group: rows rg*4..+3
    int pg = tid & 3;           // px group:  px pg*4..+3
    int rx = rg & 7;            // XOR key for wslab reads

    // staging identity: thread loads rows lrow, slots lt,lt+1
    int lrow = tid >> 3;        // 0..63
    int lt   = (tid & 7) << 1;  // 0,2,..,14
    int lkq  = tid & 7;
    int lx   = (lrow >> 2) & 7;
    const float* grow = (lrow < 32)
        ? (w2   + (size_t)lrow * OIKK + q * IKK)
        : (kern + (size_t)((oh << 5) + lrow - 32) * IKK);
    float4* wdst0 = &wslab4[lrow * 16 + ((lt + 0) ^ lx)];
    float4* wdst1 = &wslab4[lrow * 16 + ((lt + 1) ^ lx)];

    float acc[4][4];
    #pragma unroll
    for (int r = 0; r < 4; ++r)
        #pragma unroll
        for (int p = 0; p < 4; ++p) acc[r][p] = 0.f;

    // prologue: stage step 0
    {
        const float4* src = (const float4*)(grow + (lkq * 18 + 0) * 4);
        *wdst0 = src[0];
        *wdst1 = src[1];
    }
    __syncthreads();

    for (int st = 0; st < 9; ++st) {
        float4 nf0, nf1;
        if (st < 8) {   // prefetch next step into registers (latency hides under compute)
            const float4* src = (const float4*)(grow + (lkq * 18 + (st + 1) * 2) * 4);
            nf0 = src[0];
            nf1 = src[1];
        }
        // compute step st: 2 k-f4
        #pragma unroll
        for (int j = 0; j < 2; ++j) {
            int c4 = kq * 18 + st * 2 + j;
            float4 ptv0 = patch4[(pg * 4 + 0) * PF4 + c4];
            float4 ptv1 = patch4[(pg * 4 + 1) * PF4 + c4];
            float4 ptv2 = patch4[(pg * 4 + 2) * PF4 + c4];
            float4 ptv3 = patch4[(pg * 4 + 3) * PF4 + c4];
            int ts = (kq * 2 + j) ^ rx;
            float4 wv0 = wslab4[(rg * 4 + 0) * 16 + ts];
            float4 wv1 = wslab4[(rg * 4 + 1) * 16 + ts];
            float4 wv2 = wslab4[(rg * 4 + 2) * 16 + ts];
            float4 wv3 = wslab4[(rg * 4 + 3) * 16 + ts];
            #pragma unroll
            for (int p = 0; p < 4; ++p) {
                float4 pv = (p == 0) ? ptv0 : (p == 1) ? ptv1 : (p == 2) ? ptv2 : ptv3;
                acc[0][p] = fmaf(wv0.x, pv.x, acc[0][p]); acc[0][p] = fmaf(wv0.y, pv.y, acc[0][p]);
                acc[0][p] = fmaf(wv0.z, pv.z, acc[0][p]); acc[0][p] = fmaf(wv0.w, pv.w, acc[0][p]);
                acc[1][p] = fmaf(wv1.x, pv.x, acc[1][p]); acc[1][p] = fmaf(wv1.y, pv.y, acc[1][p]);
                acc[1][p] = fmaf(wv1.z, pv.z, acc[1][p]); acc[1][p] = fmaf(wv1.w, pv.w, acc[1][p]);
                acc[2][p] = fmaf(wv2.x, pv.x, acc[2][p]); acc[2][p] = fmaf(wv2.y, pv.y, acc[2][p]);
                acc[2][p] = fmaf(wv2.z, pv.z, acc[2][p]); acc[2][p] = fmaf(wv2.w, pv.w, acc[2][p]);
                acc[3][p] = fmaf(wv3.x, pv.x, acc[3][p]); acc[3][p] = fmaf(wv3.y, pv.y, acc[3][p]);
                acc[3][p] = fmaf(wv3.z, pv.z, acc[3][p]); acc[3][p] = fmaf(wv3.w, pv.w, acc[3][p]);
            }
        }
        if (st < 8) {
            __syncthreads();        // everyone done reading wslab
            *wdst0 = nf0;
            *wdst1 = nf1;
            __syncthreads();        // wslab ready
        }
    }
    __syncthreads();   // main loop done; patch now dead -> alias tred

    // ---- K-reduction via tred aliased on patch (XOR'd slots, 2048 f4 = 32KB) ----
    float4* tred = (float4*)patch;
    #pragma unroll
    for (int r = 0; r < 4; ++r) {
        int slot = ((r << 2) | pg) ^ rx;
        tred[kq * 256 + rg * 16 + slot] =
            make_float4(acc[r][0], acc[r][1], acc[r][2], acc[r][3]);
    }
    __syncthreads();

    if (tid < 256) {       // one thread per (row, pg): sum 8 kq partials
        int row = tid >> 2, pgr = tid & 3;
        int rgr = row >> 2;
        int slot = (((row & 3) << 2) | pgr) ^ (rgr & 7);
        int base = rgr * 16 + slot;
        float4 s0 = tred[base];
        #pragma unroll
        for (int k = 1; k < 8; ++k) {
            float4 v = tred[k * 256 + base];
            s0.x += v.x; s0.y += v.y; s0.z += v.z; s0.w += v.w;
        }
        if (row < 32) {
            t_sm[row][pgr * 4 + 0] = s0.x; t_sm[row][pgr * 4 + 1] = s0.y;
            t_sm[row][pgr * 4 + 2] = s0.z; t_sm[row][pgr * 4 + 3] = s0.w;
        } else {
            conv_sm[row - 32][pgr * 4 + 0] = s0.x; conv_sm[row - 32][pgr * 4 + 1] = s0.y;
            conv_sm[row - 32][pgr * 4 + 2] = s0.z; conv_sm[row - 32][pgr * 4 + 3] = s0.w;
        }
    } else if (tid < 272) { // s reduce in parallel
        int p2 = tid - 256;
        float a = 0.f;
        #pragma unroll
        for (int kc = 0; kc < 32; ++kc) a += spart[p2][kc];
        s_sm[p2] = a;
    }
    __syncthreads();

    // ---- H epilogue: inline MLP + dyn + store (1 output/thread) ----
    {
        int o  = tid & 31;
        int p2 = tid >> 5;
        int og = (oh << 5) + o;
        float cb[8];
        #pragma unroll
        for (int i = 0; i < 8; ++i) cb[i] = c[(b << 3) + i];
        int pl = (og << 4) + p2;
        float f0 = (float)(pl >> 5) * (1.0f / 32.0f);
        float f1 = (float)(pl & 31) * (1.0f / 32.0f);
        float dyn = s_sm[p2];
        #pragma unroll 4
        for (int j = 0; j < DH; ++j) {
            float v = b1[j];
            v = fmaf(f0, w1[j], v);
            v = fmaf(f1, w1[DH + j], v);
            #pragma unroll
            for (int i = 0; i < 8; ++i)
                v = fmaf(cb[i], w1[(2 + i) * DH + j], v);
            dyn = fmaf(silu_f(v), t_sm[j][p2], dyn);
        }
        out[((b * OCH + og) << 10) + (p2 << 6) + q] = conv_sm[o][p2] + bias[og] + dyn;
    }
}

extern "C" void kernel_launch(void* const* d_in, const int* in_sizes, int n_in,
                              void* d_out, int out_size, void* d_ws, size_t ws_size,
                              hipStream_t stream) {
    const float* x    = (const float*)d_in[0];
    const float* c    = (const float*)d_in[1];
    const float* kern = (const float*)d_in[2];
    const float* bias = (const float*)d_in[3];
    const float* w1   = (const float*)d_in[4];
    const float* b1   = (const float*)d_in[5];
    const float* w2   = (const float*)d_in[6];
    const float* b2   = (const float*)d_in[7];
    float* out = (float*)d_out;

    k_one<<<256, 512, 0, stream>>>(x, c, kern, bias, w1, b1, w2, b2, out);
}

// Round 16
// 20.683 us; speedup vs baseline: 1.7946x; 1.0808x over previous
//
#include <hip/hip_runtime.h>
#include <math.h>

#define CIN   64
#define HH    32
#define WW    32
#define OCH   64
#define IKK   576
#define DH    32
#define OIKK  36864
#define WSTR  296    // wslab row stride, bf16 units (592 B, 16B-mult)
#define KHALF 288

typedef __attribute__((ext_vector_type(4))) short short4v;
typedef __attribute__((ext_vector_type(8))) short short8v;
typedef __attribute__((ext_vector_type(4))) float f32x4;

__device__ __forceinline__ float silu_f(float v) {
    return v / (1.0f + __expf(-v));
}
__device__ __forceinline__ unsigned short f2bf(float f) {   // RNE f32->bf16
    unsigned int u = __float_as_uint(f);
    return (unsigned short)((u + 0x7FFFu + ((u >> 16) & 1u)) >> 16);
}
__device__ __forceinline__ float bf2f(unsigned short s) {
    return __uint_as_float(((unsigned int)s) << 16);
}

// ONE dispatch, single-writer. block = (b2,q64,oh2) = 256 x 512 threads (8 waves).
// C[64 rows][16 px] = W[64x576] . P[576x16] via mfma_f32_16x16x32_bf16:
//   waves (rt0..3, sub0..1); A-frag = wslab[row][k] bf16 (b128);
//   B-frag = patch_t[k][px] bf16 via 2x ds_read_b64_tr_b16 (lane (g,m) fetches
//   px 4(m&3)..+3 of k-row k0+g*8+(m>>2); group transpose yields B[k][col]).
// Rows 0..31 = w2 (t), 32..63 = kern (conv). wslab staged per K-half (2 stages).
__global__ __launch_bounds__(512) void k_one(
    const float* __restrict__ x, const float* __restrict__ c,
    const float* __restrict__ kern, const float* __restrict__ bias,
    const float* __restrict__ w1, const float* __restrict__ b1,
    const float* __restrict__ w2, const float* __restrict__ b2,
    float* __restrict__ out)
{
    __shared__ __align__(16) short patch_t[IKK * 16];   // [k][px] bf16, 18432 B
    __shared__ __align__(16) short wslab[64 * WSTR];    // [row][k-half] bf16, 37888 B
    __shared__ float t_sm[32][17];
    __shared__ float conv_sm[32][17];
    __shared__ float spart[16][17];
    __shared__ float s_sm[16];

    int tid = threadIdx.x;
    int bid = blockIdx.x;
    int oh  = bid & 1;
    int q   = (bid >> 1) & 63;
    int b   = bid >> 7;
    int par = q >> 5, xq = q & 31;

    // ---- stage patch: element (px=pp, k=ikk) -> patch_t[k*16+px] (bf16) ----
    for (int idx = tid; idx < 16 * IKK; idx += 512) {
        int pp  = idx / IKK;
        int ikk = idx - pp * IKK;
        int ci  = ikk / 9;
        int r   = ikk - ci * 9;
        int kh  = r / 3;
        int kw  = r - kh * 3;
        int yy  = 2 * pp + par + kh - 1;
        int xx  = xq + kw - 1;
        float v = 0.0f;
        if (yy >= 0 && yy < HH && xx >= 0 && xx < WW)
            v = x[((b * CIN + ci) * HH + yy) * WW + xx];
        patch_t[ikk * 16 + pp] = (short)f2bf(v);
    }

    // ---- wslab staging identity: thread -> (row, k-slice) ----
    int srow = tid >> 3;       // 0..63
    int s8   = tid & 7;        // covers f4 indices s8*9..+9 of the half
    const float* grow = (srow < 32)
        ? (w2   + (size_t)srow * OIKK + q * IKK)
        : (kern + (size_t)((oh << 5) + srow - 32) * IKK);

    {   // stage half 0
        const float4* gsrc = (const float4*)(grow) + s8 * 9;
        #pragma unroll
        for (int i = 0; i < 9; ++i) {
            float4 v4 = gsrc[i];
            ushort4 w4 = { f2bf(v4.x), f2bf(v4.y), f2bf(v4.z), f2bf(v4.w) };
            *(ushort4*)&wslab[srow * WSTR + (s8 * 9 + i) * 4] = w4;
        }
    }
    __syncthreads();

    int lane = tid & 63;
    int wid  = tid >> 6;
    int rt   = wid & 3;        // row-tile: rows rt*16..+15
    int sub  = wid >> 2;       // K-step split within a half
    int g    = lane >> 4;
    int m    = lane & 15;
    int s_lo = sub ? 5 : 0, s_hi = sub ? 9 : 5;

    f32x4 acc = {0.f, 0.f, 0.f, 0.f};
    unsigned pbase = (unsigned)(size_t)&patch_t[0];

    for (int half = 0; half < 2; ++half) {
        if (half == 1) {
            __syncthreads();   // everyone done with wslab half 0
            const float4* gsrc = (const float4*)(grow + KHALF) + s8 * 9;
            #pragma unroll
            for (int i = 0; i < 9; ++i) {
                float4 v4 = gsrc[i];
                ushort4 w4 = { f2bf(v4.x), f2bf(v4.y), f2bf(v4.z), f2bf(v4.w) };
                *(ushort4*)&wslab[srow * WSTR + (s8 * 9 + i) * 4] = w4;
            }
            __syncthreads();
        }
        for (int stp = s_lo; stp < s_hi; ++stp) {
            short8v a = *(const short8v*)&wslab[(rt * 16 + m) * WSTR + stp * 32 + g * 8];
            int krow = half * KHALF + stp * 32 + g * 8 + (m >> 2);
            unsigned baddr = pbase + (unsigned)(krow * 32 + (m & 3) * 8);
            short4v lo, hi;
            asm volatile("ds_read_b64_tr_b16 %0, %1" : "=v"(lo) : "v"(baddr));
            asm volatile("ds_read_b64_tr_b16 %0, %1 offset:128" : "=v"(hi) : "v"(baddr));
            asm volatile("s_waitcnt lgkmcnt(0)" ::: "memory");
            __builtin_amdgcn_sched_barrier(0);
            short8v bfr = { lo[0], lo[1], lo[2], lo[3], hi[0], hi[1], hi[2], hi[3] };
            acc = __builtin_amdgcn_mfma_f32_16x16x32_bf16(a, bfr, acc, 0, 0, 0);
        }
    }
    __syncthreads();   // wslab dead -> alias reduction buffer

    f32x4* red = (f32x4*)wslab;
    if (sub == 1) {
        red[rt * 64 + lane] = acc;
    } else {
        // s partials (tid<256): px = tid>>4, kc = tid&15, 36 k each
        int px = tid >> 4, kc = tid & 15;
        const float* b2q = b2 + q * IKK + kc * 36;
        float a0 = 0.f;
        #pragma unroll
        for (int i = 0; i < 36; ++i)
            a0 = fmaf(bf2f((unsigned short)patch_t[(kc * 36 + i) * 16 + px]), b2q[i], a0);
        spart[px][kc] = a0;
    }
    __syncthreads();

    if (sub == 0) {
        f32x4 o = red[rt * 64 + lane];
        #pragma unroll
        for (int r = 0; r < 4; ++r) {
            int row = rt * 16 + g * 4 + r;     // C/D: row=(lane>>4)*4+reg, col=lane&15
            float v = acc[r] + o[r];
            if (row < 32) t_sm[row][m] = v;
            else          conv_sm[row - 32][m] = v;
        }
    } else if (rt == 0 && lane < 16) {         // tids 256..271: s reduce
        float a0 = 0.f;
        #pragma unroll
        for (int kc = 0; kc < 16; ++kc) a0 += spart[lane][kc];
        s_sm[lane] = a0;
    }
    __syncthreads();

    // ---- H epilogue: inline MLP + dyn + store (1 output/thread) ----
    {
        int o  = tid & 31;
        int p2 = tid >> 5;
        int og = (oh << 5) + o;
        float cb[8];
        #pragma unroll
        for (int i = 0; i < 8; ++i) cb[i] = c[(b << 3) + i];
        int pl = (og << 4) + p2;
        float f0 = (float)(pl >> 5) * (1.0f / 32.0f);
        float f1 = (float)(pl & 31) * (1.0f / 32.0f);
        float dyn = s_sm[p2];
        #pragma unroll 4
        for (int j = 0; j < DH; ++j) {
            float v = b1[j];
            v = fmaf(f0, w1[j], v);
            v = fmaf(f1, w1[DH + j], v);
            #pragma unroll
            for (int i = 0; i < 8; ++i)
                v = fmaf(cb[i], w1[(2 + i) * DH + j], v);
            dyn = fmaf(silu_f(v), t_sm[j][p2], dyn);
        }
        out[((b * OCH + og) << 10) + (p2 << 6) + q] = conv_sm[o][p2] + bias[og] + dyn;
    }
}

extern "C" void kernel_launch(void* const* d_in, const int* in_sizes, int n_in,
                              void* d_out, int out_size, void* d_ws, size_t ws_size,
                              hipStream_t stream) {
    const float* x    = (const float*)d_in[0];
    const float* c    = (const float*)d_in[1];
    const float* kern = (const float*)d_in[2];
    const float* bias = (const float*)d_in[3];
    const float* w1   = (const float*)d_in[4];
    const float* b1   = (const float*)d_in[5];
    const float* w2   = (const float*)d_in[6];
    const float* b2   = (const float*)d_in[7];
    float* out = (float*)d_out;

    k_one<<<256, 512, 0, stream>>>(x, c, kern, bias, w1, b1, w2, b2, out);
}

// Round 17
// 20.170 us; speedup vs baseline: 1.8403x; 1.0254x over previous
//
#include <hip/hip_runtime.h>
#include <hip/hip_bf16.h>
#include <math.h>

#define CIN   64
#define HH    32
#define WW    32
#define OCH   64
#define IKK   576
#define DH    32
#define OIKK  36864
#define WSTR  296    // wslab row stride, bf16 units (592 B, 16B-mult)
#define KHALF 288

typedef __attribute__((ext_vector_type(4))) short short4v;
typedef __attribute__((ext_vector_type(8))) short short8v;
typedef __attribute__((ext_vector_type(4))) float f32x4;

__device__ __forceinline__ float silu_f(float v) {
    return v / (1.0f + __expf(-v));
}
__device__ __forceinline__ unsigned short f2bf(float f) {   // HW RNE cvt
    __hip_bfloat16 h = __float2bfloat16(f);
    return *reinterpret_cast<unsigned short*>(&h);
}
__device__ __forceinline__ float bf2f(unsigned short s) {
    return __uint_as_float(((unsigned int)s) << 16);
}

// ONE dispatch, single-writer. block = (b2,q64,oh2) = 256 x 512 threads (8 waves).
// C[64 rows][16 px] = W[64x576] . P[576x16] via mfma_f32_16x16x32_bf16.
// T14 async-split: half-1 weight loads issued BEFORE barrier 1, so their L2
// latency hides under half-0 compute; store phase has zero wait.
__global__ __launch_bounds__(512) void k_one(
    const float* __restrict__ x, const float* __restrict__ c,
    const float* __restrict__ kern, const float* __restrict__ bias,
    const float* __restrict__ w1, const float* __restrict__ b1,
    const float* __restrict__ w2, const float* __restrict__ b2,
    float* __restrict__ out)
{
    __shared__ __align__(16) short patch_t[IKK * 16];   // [k][px] bf16, 18432 B
    __shared__ __align__(16) short wslab[64 * WSTR];    // [row][k-half] bf16, 37888 B
    __shared__ float t_sm[32][17];
    __shared__ float conv_sm[32][17];
    __shared__ float spart[16][17];
    __shared__ float s_sm[16];

    int tid = threadIdx.x;
    int bid = blockIdx.x;
    int oh  = bid & 1;
    int q   = (bid >> 1) & 63;
    int b   = bid >> 7;
    int par = q >> 5, xq = q & 31;

    // ---- wslab staging identity + issue half-0 loads ----
    int srow = tid >> 3;       // 0..63
    int s8   = tid & 7;        // f4 indices s8*9..+9 of each half
    const float* grow = (srow < 32)
        ? (w2   + (size_t)srow * OIKK + q * IKK)
        : (kern + (size_t)((oh << 5) + srow - 32) * IKK);
    const float4* g0 = (const float4*)(grow) + s8 * 9;
    const float4* g1 = (const float4*)(grow + KHALF) + s8 * 9;

    float4 h0[9];
    #pragma unroll
    for (int i = 0; i < 9; ++i) h0[i] = g0[i];

    // ---- stage patch (incremental pp/ikk, no divisions for pp) ----
    {
        int pp = 0, ikk = tid;   // tid < 512 < 576
        #pragma unroll
        for (int it = 0; it < 18; ++it) {
            int ci = ikk / 9;
            int r  = ikk - ci * 9;
            int kh = r / 3;
            int kw = r - kh * 3;
            int yy = 2 * pp + par + kh - 1;
            int xx = xq + kw - 1;
            float v = 0.0f;
            if (yy >= 0 && yy < HH && xx >= 0 && xx < WW)
                v = x[((b * CIN + ci) * HH + yy) * WW + xx];
            patch_t[ikk * 16 + pp] = (short)f2bf(v);
            ikk += 512;
            if (ikk >= IKK) { ikk -= IKK; ++pp; }
        }
    }

    // ---- store half-0, then ISSUE half-1 loads (complete during compute-0) ----
    #pragma unroll
    for (int i = 0; i < 9; ++i) {
        ushort4 w4 = { f2bf(h0[i].x), f2bf(h0[i].y), f2bf(h0[i].z), f2bf(h0[i].w) };
        *(ushort4*)&wslab[srow * WSTR + (s8 * 9 + i) * 4] = w4;
    }
    float4 h1[9];
    #pragma unroll
    for (int i = 0; i < 9; ++i) h1[i] = g1[i];
    __syncthreads();

    int lane = tid & 63;
    int wid  = tid >> 6;
    int rt   = wid & 3;        // row-tile: rows rt*16..+15
    int sub  = wid >> 2;       // K-step split within a half
    int g    = lane >> 4;
    int m    = lane & 15;
    int s_lo = sub ? 5 : 0, s_hi = sub ? 9 : 5;

    f32x4 acc = {0.f, 0.f, 0.f, 0.f};
    unsigned pbase = (unsigned)(size_t)&patch_t[0];

    // ---- compute half 0 ----
    for (int stp = s_lo; stp < s_hi; ++stp) {
        short8v a = *(const short8v*)&wslab[(rt * 16 + m) * WSTR + stp * 32 + g * 8];
        int krow = stp * 32 + g * 8 + (m >> 2);
        unsigned baddr = pbase + (unsigned)(krow * 32 + (m & 3) * 8);
        short4v lo, hi;
        asm volatile("ds_read_b64_tr_b16 %0, %1" : "=v"(lo) : "v"(baddr));
        asm volatile("ds_read_b64_tr_b16 %0, %1 offset:128" : "=v"(hi) : "v"(baddr));
        asm volatile("s_waitcnt lgkmcnt(0)" ::: "memory");
        __builtin_amdgcn_sched_barrier(0);
        short8v bfr = { lo[0], lo[1], lo[2], lo[3], hi[0], hi[1], hi[2], hi[3] };
        acc = __builtin_amdgcn_mfma_f32_16x16x32_bf16(a, bfr, acc, 0, 0, 0);
    }
    __syncthreads();

    // ---- store half-1 from registers (no global wait) ----
    #pragma unroll
    for (int i = 0; i < 9; ++i) {
        ushort4 w4 = { f2bf(h1[i].x), f2bf(h1[i].y), f2bf(h1[i].z), f2bf(h1[i].w) };
        *(ushort4*)&wslab[srow * WSTR + (s8 * 9 + i) * 4] = w4;
    }
    __syncthreads();

    // ---- compute half 1 ----
    for (int stp = s_lo; stp < s_hi; ++stp) {
        short8v a = *(const short8v*)&wslab[(rt * 16 + m) * WSTR + stp * 32 + g * 8];
        int krow = KHALF + stp * 32 + g * 8 + (m >> 2);
        unsigned baddr = pbase + (unsigned)(krow * 32 + (m & 3) * 8);
        short4v lo, hi;
        asm volatile("ds_read_b64_tr_b16 %0, %1" : "=v"(lo) : "v"(baddr));
        asm volatile("ds_read_b64_tr_b16 %0, %1 offset:128" : "=v"(hi) : "v"(baddr));
        asm volatile("s_waitcnt lgkmcnt(0)" ::: "memory");
        __builtin_amdgcn_sched_barrier(0);
        short8v bfr = { lo[0], lo[1], lo[2], lo[3], hi[0], hi[1], hi[2], hi[3] };
        acc = __builtin_amdgcn_mfma_f32_16x16x32_bf16(a, bfr, acc, 0, 0, 0);
    }
    __syncthreads();   // wslab dead -> alias reduction buffer

    f32x4* red = (f32x4*)wslab;
    if (sub == 1) {
        red[rt * 64 + lane] = acc;
    } else {
        // s partials (tid<256): px = tid>>4, kc = tid&15, 36 k each
        int px = tid >> 4, kc = tid & 15;
        const float* b2q = b2 + q * IKK + kc * 36;
        float a0 = 0.f;
        #pragma unroll
        for (int i = 0; i < 36; ++i)
            a0 = fmaf(bf2f((unsigned short)patch_t[(kc * 36 + i) * 16 + px]), b2q[i], a0);
        spart[px][kc] = a0;
    }
    __syncthreads();

    if (sub == 0) {
        f32x4 o = red[rt * 64 + lane];
        #pragma unroll
        for (int r = 0; r < 4; ++r) {
            int row = rt * 16 + g * 4 + r;     // C/D: row=(lane>>4)*4+reg, col=lane&15
            float v = acc[r] + o[r];
            if (row < 32) t_sm[row][m] = v;
            else          conv_sm[row - 32][m] = v;
        }
    } else if (rt == 0 && lane < 16) {         // tids 256..271: s reduce
        float a0 = 0.f;
        #pragma unroll
        for (int kc = 0; kc < 16; ++kc) a0 += spart[lane][kc];
        s_sm[lane] = a0;
    }
    __syncthreads();

    // ---- H epilogue: inline MLP + dyn + store (1 output/thread) ----
    {
        int o  = tid & 31;
        int p2 = tid >> 5;
        int og = (oh << 5) + o;
        float cb[8];
        #pragma unroll
        for (int i = 0; i < 8; ++i) cb[i] = c[(b << 3) + i];
        int pl = (og << 4) + p2;
        float f0 = (float)(pl >> 5) * (1.0f / 32.0f);
        float f1 = (float)(pl & 31) * (1.0f / 32.0f);
        float dyn = s_sm[p2];
        #pragma unroll 4
        for (int j = 0; j < DH; ++j) {
            float v = b1[j];
            v = fmaf(f0, w1[j], v);
            v = fmaf(f1, w1[DH + j], v);
            #pragma unroll
            for (int i = 0; i < 8; ++i)
                v = fmaf(cb[i], w1[(2 + i) * DH + j], v);
            dyn = fmaf(silu_f(v), t_sm[j][p2], dyn);
        }
        out[((b * OCH + og) << 10) + (p2 << 6) + q] = conv_sm[o][p2] + bias[og] + dyn;
    }
}

extern "C" void kernel_launch(void* const* d_in, const int* in_sizes, int n_in,
                              void* d_out, int out_size, void* d_ws, size_t ws_size,
                              hipStream_t stream) {
    const float* x    = (const float*)d_in[0];
    const float* c    = (const float*)d_in[1];
    const float* kern = (const float*)d_in[2];
    const float* bias = (const float*)d_in[3];
    const float* w1   = (const float*)d_in[4];
    const float* b1   = (const float*)d_in[5];
    const float* w2   = (const float*)d_in[6];
    const float* b2   = (const float*)d_in[7];
    float* out = (float*)d_out;

    k_one<<<256, 512, 0, stream>>>(x, c, kern, bias, w1, b1, w2, b2, out);
}